// Round 1
// baseline (441.700 us; speedup 1.0000x reference)
//
#include <hip/hip_runtime.h>
#include <stdint.h>

typedef unsigned short u16;
typedef unsigned char u8;
typedef __attribute__((ext_vector_type(8))) short short8x;
typedef __attribute__((ext_vector_type(4))) float f32x4;

#define DEV static __device__ __forceinline__

DEV u16 f2bf(float f) {
  union { float f; unsigned u; } v; v.f = f;
  unsigned r = v.u + 0x7FFFu + ((v.u >> 16) & 1u);
  return (u16)(r >> 16);
}
DEV int imin(int a, int b) { return a < b ? a : b; }
DEV int imax(int a, int b) { return a > b ? a : b; }

// ---------------------------------------------------------------------------
// Weight convert+transpose: w[k][n] fp32 -> wt[mat][n][k] bf16 (7 mats)
struct WPtrs { const float* p[7]; };

__global__ __launch_bounds__(256) void wconv_kernel(WPtrs wp, u16* __restrict__ wt) {
  const int mat = blockIdx.y;
  const int kt = blockIdx.x % 12, nt = blockIdx.x / 12;
  const float* __restrict__ w = wp.p[mat];
  __shared__ float tile[64][72];
  const int t = threadIdx.x;
  {
    const int kk = t >> 2, n0 = (t & 3) * 16;
    const float* src = w + (size_t)(kt * 64 + kk) * 768 + nt * 64 + n0;
#pragma unroll
    for (int i = 0; i < 4; ++i)
      *(float4*)&tile[kk][n0 + i * 4] = *(const float4*)(src + i * 4);
  }
  __syncthreads();
  {
    const int nn = t >> 2, k0 = (t & 3) * 16;
    u16* dst = wt + (size_t)(mat * 768 + nt * 64 + nn) * 768 + kt * 64 + k0;
    short8x v0, v1;
#pragma unroll
    for (int j = 0; j < 8; ++j) {
      v0[j] = (short)f2bf(tile[k0 + j][nn]);
      v1[j] = (short)f2bf(tile[k0 + 8 + j][nn]);
    }
    *(short8x*)dst = v0;
    *(short8x*)(dst + 8) = v1;
  }
}

// ---------------------------------------------------------------------------
// h = emb[x] + pos  -> bf16  (8192 x 768)
__global__ __launch_bounds__(256) void embed_kernel(const int* __restrict__ x, const float* __restrict__ emb,
                                                    const float* __restrict__ pos, u16* __restrict__ hb) {
  const int n4 = 2 * 4096 * 192;
  for (int i = blockIdx.x * 256 + threadIdx.x; i < n4; i += gridDim.x * 256) {
    const int r = i / 192;
    const int d4 = i - r * 192;
    const int s = r & 4095;
    const int tok = x[r];
    const float4 e = *(const float4*)(emb + (size_t)tok * 768 + d4 * 4);
    const float4 p = *(const float4*)(pos + (size_t)s * 768 + d4 * 4);
    union { u16 u[4]; uint2 v; } o;
    o.u[0] = f2bf(e.x + p.x);
    o.u[1] = f2bf(e.y + p.y);
    o.u[2] = f2bf(e.z + p.z);
    o.u[3] = f2bf(e.w + p.w);
    *(uint2*)(hb + (size_t)r * 768 + d4 * 4) = o.v;
  }
}

// ---------------------------------------------------------------------------
__global__ __launch_bounds__(256) void isg_kernel(const int* __restrict__ clss, u8* __restrict__ isg) {
  const int t = threadIdx.x;
  for (int i = t; i < 4096; i += 256) isg[i] = 0;
  __syncthreads();
  if (t < 64) isg[clss[t]] = 1;
}

// ---------------------------------------------------------------------------
// 128x128x32 bf16 MFMA GEMM, B pre-transposed (N x K).
// MODE 0: A=h (8192x768), Bt=Wt cat (4608x768): write q,k,v,kg,vg,qg in (B,H,S,DH) bf16
// MODE 1: A=attn_out bf16 (8192x768), Bt=woT: write fp32 d_out row-major
struct Outs6 { u16* p[6]; };

template <int MODE>
__global__ __launch_bounds__(256) void gemm_kernel(const u16* __restrict__ A, const u16* __restrict__ Bt,
                                                   Outs6 outs, float* __restrict__ outF) {
  __shared__ u16 smA[128 * 32];
  __shared__ u16 smB[128 * 32];
  const int t = threadIdx.x;
  const int l = t & 63, w = t >> 6;
  const int l15 = l & 15, grp = l >> 4;
  const int wm = w >> 1, wn = w & 1;
  const int m0 = blockIdx.y * 128, n0 = blockIdx.x * 128;
  const f32x4 zero4 = {0.f, 0.f, 0.f, 0.f};
  f32x4 acc[4][4];
#pragma unroll
  for (int mi = 0; mi < 4; ++mi)
#pragma unroll
    for (int ni = 0; ni < 4; ++ni) acc[mi][ni] = zero4;

  const int r = t >> 2, kc = t & 3;
  for (int kb = 0; kb < 24; ++kb) {
    __syncthreads();
    {
      const size_t ko = (size_t)kb * 32 + kc * 8;
      *(float4*)(smA + r * 32 + kc * 8) = *(const float4*)(A + (size_t)(m0 + r) * 768 + ko);
      *(float4*)(smA + (64 + r) * 32 + kc * 8) = *(const float4*)(A + (size_t)(m0 + 64 + r) * 768 + ko);
      *(float4*)(smB + r * 32 + kc * 8) = *(const float4*)(Bt + (size_t)(n0 + r) * 768 + ko);
      *(float4*)(smB + (64 + r) * 32 + kc * 8) = *(const float4*)(Bt + (size_t)(n0 + 64 + r) * 768 + ko);
    }
    __syncthreads();
    short8x af[4], bfr[4];
#pragma unroll
    for (int mi = 0; mi < 4; ++mi)
      af[mi] = *(const short8x*)(smA + (wm * 64 + mi * 16 + l15) * 32 + grp * 8);
#pragma unroll
    for (int ni = 0; ni < 4; ++ni)
      bfr[ni] = *(const short8x*)(smB + (wn * 64 + ni * 16 + l15) * 32 + grp * 8);
#pragma unroll
    for (int mi = 0; mi < 4; ++mi)
#pragma unroll
      for (int ni = 0; ni < 4; ++ni)
        acc[mi][ni] = __builtin_amdgcn_mfma_f32_16x16x32_bf16(af[mi], bfr[ni], acc[mi][ni], 0, 0, 0);
  }

  if (MODE == 0) {
    const int mat = blockIdx.x / 6;               // 6 col-blocks per 768-wide matrix
    const int inn0 = n0 - mat * 768 + wn * 64;
    const float scl = (mat == 0 || mat == 5) ? 0.125f : 1.0f;  // q, qg scaled by DH^-0.5
    u16* __restrict__ base = outs.p[mat];
#pragma unroll
    for (int mi = 0; mi < 4; ++mi)
#pragma unroll
      for (int ni = 0; ni < 4; ++ni) {
        const int col = inn0 + ni * 16 + l15;
        const int hd = col >> 6, dh = col & 63;
#pragma unroll
        for (int rr = 0; rr < 4; ++rr) {
          const int row = m0 + wm * 64 + mi * 16 + grp * 4 + rr;
          const int b = row >> 12, s = row & 4095;
          base[((size_t)(b * 12 + hd) * 4096 + s) * 64 + dh] = f2bf(acc[mi][ni][rr] * scl);
        }
      }
  } else {
#pragma unroll
    for (int mi = 0; mi < 4; ++mi)
#pragma unroll
      for (int rr = 0; rr < 4; ++rr) {
        const int row = m0 + wm * 64 + mi * 16 + grp * 4 + rr;
#pragma unroll
        for (int ni = 0; ni < 4; ++ni) {
          const int col = n0 + wn * 64 + ni * 16 + l15;
          outF[(size_t)row * 768 + col] = acc[mi][ni][rr];
        }
      }
  }
}

// ---------------------------------------------------------------------------
// (B,H,S,DH) -> (B,H,DH,S) bf16, two buffers (v->vT, vg->vgT)
__global__ __launch_bounds__(256) void transp_kernel(const u16* __restrict__ in0, u16* __restrict__ out0,
                                                     const u16* __restrict__ in1, u16* __restrict__ out1) {
  const u16* src = blockIdx.y ? in1 : in0;
  u16* dst = blockIdx.y ? out1 : out0;
  const int bh = blockIdx.x >> 6;
  const int s0 = (blockIdx.x & 63) << 6;
  __shared__ u16 tile[64][80];
  const int t = threadIdx.x;
  {
    const int sl = t >> 2, d0 = (t & 3) * 16;
    const u16* p = src + ((size_t)bh * 4096 + s0 + sl) * 64 + d0;
    *(short8x*)&tile[sl][d0] = *(const short8x*)p;
    *(short8x*)&tile[sl][d0 + 8] = *(const short8x*)(p + 8);
  }
  __syncthreads();
  {
    const int dh = t >> 2, q0 = (t & 3) * 16;
    short8x v0, v1;
#pragma unroll
    for (int j = 0; j < 8; ++j) {
      v0[j] = (short)tile[q0 + j][dh];
      v1[j] = (short)tile[q0 + 8 + j][dh];
    }
    u16* o = dst + ((size_t)bh * 64 + dh) * 4096 + s0 + q0;
    *(short8x*)o = v0;
    *(short8x*)(o + 8) = v1;
  }
}

// ---------------------------------------------------------------------------
// Gather K rows at clss -> kcls[bh][g][dh]; v rows at clss transposed -> vtcls[bh][dh][g]; mask at clss.
__global__ __launch_bounds__(256) void gcls_kernel(const u16* __restrict__ kB, const u16* __restrict__ vB,
                                                   const int* __restrict__ clss, const int* __restrict__ mask,
                                                   u16* __restrict__ kcls, u16* __restrict__ vtcls,
                                                   u8* __restrict__ mcls) {
  const int bh = blockIdx.x;
  const int b = bh / 12;
  __shared__ u16 tile[64][80];
  const int t = threadIdx.x;
  {
    const int g = t >> 2, d0 = (t & 3) * 16;
    const int row = clss[g];
    const u16* pk = kB + ((size_t)bh * 4096 + row) * 64 + d0;
    u16* ok = kcls + ((size_t)bh * 64 + g) * 64 + d0;
    *(short8x*)ok = *(const short8x*)pk;
    *(short8x*)(ok + 8) = *(const short8x*)(pk + 8);
    const u16* pv = vB + ((size_t)bh * 4096 + row) * 64 + d0;
    *(short8x*)&tile[g][d0] = *(const short8x*)pv;
    *(short8x*)&tile[g][d0 + 8] = *(const short8x*)(pv + 8);
  }
  if (t < 64) mcls[b * 64 + t] = (mask[(size_t)b * 4096 + clss[t]] != 0) ? 1 : 0;
  __syncthreads();
  {
    const int dh = t >> 2, g0 = (t & 3) * 16;
    short8x v0, v1;
#pragma unroll
    for (int j = 0; j < 8; ++j) {
      v0[j] = (short)tile[g0 + j][dh];
      v1[j] = (short)tile[g0 + 8 + j][dh];
    }
    u16* o = vtcls + ((size_t)bh * 64 + dh) * 64 + g0;
    *(short8x*)o = v0;
    *(short8x*)(o + 8) = v1;
  }
}

// ---------------------------------------------------------------------------
// Band + global-key attention. One block per (b,h,chunk); wave w owns 64 queries.
// Flash loop over 64-key tiles: band tiles t in [max(w,4-4c), min(w+8,11,67-4c)], then the 64 clss keys.
__global__ __launch_bounds__(256) void band_kernel(
    const u16* __restrict__ qB, const u16* __restrict__ kB, const u16* __restrict__ vT,
    const u16* __restrict__ kcls, const u16* __restrict__ vtcls, const u8* __restrict__ mcls,
    const int* __restrict__ mask, const u8* __restrict__ isg,
    u16* __restrict__ aout) {
  const int bid = blockIdx.x;
  const int c = bid & 15;
  const int h = (bid >> 4) % 12;
  const int b = bid / 192;
  const int t = threadIdx.x;
  const int w = t >> 6, l = t & 63, l15 = l & 15, grp = l >> 4;
  const int bh = b * 12 + h;
  const int qlo = c * 256 + w * 64;

  __shared__ u16 Pt[4][4096];  // per-wave 64x64 bf16 P tile (XOR-swizzled)
  u16* P = Pt[w];

  const u16* qb = qB + ((size_t)bh * 4096 + qlo) * 64;
  short8x qf[4][2];
#pragma unroll
  for (int qi = 0; qi < 4; ++qi)
#pragma unroll
    for (int ks = 0; ks < 2; ++ks)
      qf[qi][ks] = *(const short8x*)(qb + (qi * 16 + l15) * 64 + ks * 32 + grp * 8);

  const f32x4 zero4 = {0.f, 0.f, 0.f, 0.f};
  f32x4 accD[4][4];
  float mst[4][4], lst[4][4];
#pragma unroll
  for (int qi = 0; qi < 4; ++qi)
#pragma unroll
    for (int j = 0; j < 4; ++j) { accD[qi][j] = zero4; mst[qi][j] = -60.f; lst[qi][j] = 0.f; }

  const u16* kbh = kB + (size_t)bh * 4096 * 64;
  const u16* vbh = vT + (size_t)bh * 64 * 4096;
  const u16* kcb = kcls + (size_t)bh * 4096;
  const u16* vcb = vtcls + (size_t)bh * 4096;

  const int tlo = (c == 0) ? imax(w, 4) : w;
  const int thi = imin(w + 8, imin(11, 67 - 4 * c));

  for (int tt = tlo; tt <= thi + 1; ++tt) {
    const bool isG = (tt == thi + 1);
    const int kbase = isG ? 0 : (c * 256 - 256 + tt * 64);

    int kok[4], keyv[4];
    const u16* krow[4];
#pragma unroll
    for (int kj = 0; kj < 4; ++kj) {
      const int key = kbase + kj * 16 + l15;
      keyv[kj] = key;
      if (isG) {
        kok[kj] = mcls[b * 64 + key];
        krow[kj] = kcb + key * 64;
      } else {
        kok[kj] = (int)(isg[key] == 0) & (int)(mask[b * 4096 + key] != 0);
        krow[kj] = kbh + (size_t)key * 64;
      }
    }

    f32x4 sf[4][4];
#pragma unroll
    for (int qi = 0; qi < 4; ++qi)
#pragma unroll
      for (int kj = 0; kj < 4; ++kj) sf[qi][kj] = zero4;
#pragma unroll
    for (int ks = 0; ks < 2; ++ks) {
      short8x kfk[4];
#pragma unroll
      for (int kj = 0; kj < 4; ++kj) kfk[kj] = *(const short8x*)(krow[kj] + ks * 32 + grp * 8);
#pragma unroll
      for (int qi = 0; qi < 4; ++qi)
#pragma unroll
        for (int kj = 0; kj < 4; ++kj)
          sf[qi][kj] = __builtin_amdgcn_mfma_f32_16x16x32_bf16(qf[qi][ks], kfk[kj], sf[qi][kj], 0, 0, 0);
    }

    // mask + online softmax (stats per (qi,rr) ~ rows match C-layout rows)
#pragma unroll
    for (int qi = 0; qi < 4; ++qi) {
      const int q0 = qlo + qi * 16 + grp * 4;
      float tm[4];
#pragma unroll
      for (int rr = 0; rr < 4; ++rr) tm[rr] = -1e30f;
#pragma unroll
      for (int kj = 0; kj < 4; ++kj)
#pragma unroll
        for (int rr = 0; rr < 4; ++rr) {
          int valid = kok[kj];
          if (!isG) {
            const int rel = keyv[kj] - (q0 + rr);
            valid = valid & (int)(rel >= -256) & (int)(rel <= 256);
          }
          const float sv = valid ? sf[qi][kj][rr] : -1e30f;
          sf[qi][kj][rr] = sv;
          tm[rr] = fmaxf(tm[rr], sv);
        }
#pragma unroll
      for (int rr = 0; rr < 4; ++rr) {
        float v = tm[rr];
        v = fmaxf(v, __shfl_xor(v, 1));
        v = fmaxf(v, __shfl_xor(v, 2));
        v = fmaxf(v, __shfl_xor(v, 4));
        v = fmaxf(v, __shfl_xor(v, 8));
        const float mo = mst[qi][rr];
        const float mn = fmaxf(mo, v);  // floor -60 keeps masked-exp at exact 0
        const float sc = __expf(mo - mn);
        float ps = 0.f;
#pragma unroll
        for (int kj = 0; kj < 4; ++kj) {
          const float p = __expf(sf[qi][kj][rr] - mn);
          sf[qi][kj][rr] = p;
          ps += p;
        }
        ps += __shfl_xor(ps, 1);
        ps += __shfl_xor(ps, 2);
        ps += __shfl_xor(ps, 4);
        ps += __shfl_xor(ps, 8);
        lst[qi][rr] = lst[qi][rr] * sc + ps;
        mst[qi][rr] = mn;
#pragma unroll
        for (int dj = 0; dj < 4; ++dj) accD[qi][dj][rr] *= sc;
      }
    }

    // P -> LDS bf16 (row q*128B + key*2B, XOR swizzle on bits 4-6 by row&7)
#pragma unroll
    for (int qi = 0; qi < 4; ++qi)
#pragma unroll
      for (int rr = 0; rr < 4; ++rr) {
        const int ql = qi * 16 + grp * 4 + rr;
        const int swz = (ql & 7) << 4;
        char* rowp = (char*)P + ql * 128;
#pragma unroll
        for (int kj = 0; kj < 4; ++kj) {
          const int byo = ((kj * 16 + l15) * 2) ^ swz;
          *(u16*)(rowp + byo) = f2bf(sf[qi][kj][rr]);
        }
      }
    asm volatile("s_waitcnt lgkmcnt(0)" ::: "memory");
    __builtin_amdgcn_sched_barrier(0);

    // PV: A = P (from LDS), B = vT (global, K-contiguous)
#pragma unroll
    for (int ks = 0; ks < 2; ++ks) {
      short8x pak[4], vfk[4];
#pragma unroll
      for (int qi = 0; qi < 4; ++qi) {
        const int ql = qi * 16 + l15;
        const int byo = (ql * 128 + ks * 64 + grp * 16) ^ ((ql & 7) << 4);
        pak[qi] = *(const short8x*)((const char*)P + byo);
      }
#pragma unroll
      for (int dj = 0; dj < 4; ++dj) {
        const int dh = dj * 16 + l15;
        const u16* vr = isG ? (vcb + dh * 64) : (vbh + (size_t)dh * 4096 + kbase);
        vfk[dj] = *(const short8x*)(vr + ks * 32 + grp * 8);
      }
#pragma unroll
      for (int qi = 0; qi < 4; ++qi)
#pragma unroll
        for (int dj = 0; dj < 4; ++dj)
          accD[qi][dj] = __builtin_amdgcn_mfma_f32_16x16x32_bf16(pak[qi], vfk[dj], accD[qi][dj], 0, 0, 0);
    }
    asm volatile("s_waitcnt lgkmcnt(0)" ::: "memory");
    __builtin_amdgcn_sched_barrier(0);
  }

  // finalize: divide by row sums, store (B,S,D) bf16
  u16* ob = aout + ((size_t)b * 4096 + qlo) * 768 + h * 64;
#pragma unroll
  for (int qi = 0; qi < 4; ++qi)
#pragma unroll
    for (int rr = 0; rr < 4; ++rr) {
      const float inv = 1.f / lst[qi][rr];
      const int row = qi * 16 + grp * 4 + rr;
#pragma unroll
      for (int dj = 0; dj < 4; ++dj)
        ob[(size_t)row * 768 + dj * 16 + l15] = f2bf(accD[qi][dj][rr] * inv);
    }
}

// ---------------------------------------------------------------------------
// Global-token attention: qg[clss] vs kg (all S), out=softmax@vg; overwrites clss rows of aout.
// One block per (b,h); wave w owns 16 queries over all 4096 keys.
__global__ __launch_bounds__(256) void og_kernel(
    const u16* __restrict__ qgB, const u16* __restrict__ kgB, const u16* __restrict__ vgT,
    const int* __restrict__ clss, const int* __restrict__ mask,
    u16* __restrict__ aout) {
  const int bh = blockIdx.x;
  const int b = bh / 12, h = bh % 12;
  const int t = threadIdx.x, w = t >> 6, l = t & 63, l15 = l & 15, grp = l >> 4;

  __shared__ u16 Pt[4][1024];  // per-wave 16x64 bf16 P tile
  u16* P = Pt[w];

  const u16* qgb = qgB + (size_t)bh * 4096 * 64;
  const u16* kgb = kgB + (size_t)bh * 4096 * 64;
  const u16* vgb = vgT + (size_t)bh * 64 * 4096;

  const int srow_l = clss[w * 16 + l15];
  short8x qf[2];
  qf[0] = *(const short8x*)(qgb + (size_t)srow_l * 64 + grp * 8);
  qf[1] = *(const short8x*)(qgb + (size_t)srow_l * 64 + 32 + grp * 8);

  const f32x4 zero4 = {0.f, 0.f, 0.f, 0.f};
  f32x4 accD[4];
  float mst[4], lst[4];
#pragma unroll
  for (int j = 0; j < 4; ++j) { accD[j] = zero4; mst[j] = -60.f; lst[j] = 0.f; }

  for (int tt = 0; tt < 64; ++tt) {
    const int kbase = tt * 64;
    int kok[4];
    f32x4 sf[4];
#pragma unroll
    for (int kj = 0; kj < 4; ++kj) {
      sf[kj] = zero4;
      kok[kj] = (mask[b * 4096 + kbase + kj * 16 + l15] != 0);
    }
#pragma unroll
    for (int ks = 0; ks < 2; ++ks) {
      short8x kfk[4];
#pragma unroll
      for (int kj = 0; kj < 4; ++kj)
        kfk[kj] = *(const short8x*)(kgb + (size_t)(kbase + kj * 16 + l15) * 64 + ks * 32 + grp * 8);
#pragma unroll
      for (int kj = 0; kj < 4; ++kj)
        sf[kj] = __builtin_amdgcn_mfma_f32_16x16x32_bf16(qf[ks], kfk[kj], sf[kj], 0, 0, 0);
    }
    float tm[4];
#pragma unroll
    for (int rr = 0; rr < 4; ++rr) tm[rr] = -1e30f;
#pragma unroll
    for (int kj = 0; kj < 4; ++kj)
#pragma unroll
      for (int rr = 0; rr < 4; ++rr) {
        const float sv = kok[kj] ? sf[kj][rr] : -1e30f;
        sf[kj][rr] = sv;
        tm[rr] = fmaxf(tm[rr], sv);
      }
#pragma unroll
    for (int rr = 0; rr < 4; ++rr) {
      float v = tm[rr];
      v = fmaxf(v, __shfl_xor(v, 1));
      v = fmaxf(v, __shfl_xor(v, 2));
      v = fmaxf(v, __shfl_xor(v, 4));
      v = fmaxf(v, __shfl_xor(v, 8));
      const float mo = mst[rr];
      const float mn = fmaxf(mo, v);
      const float sc = __expf(mo - mn);
      float ps = 0.f;
#pragma unroll
      for (int kj = 0; kj < 4; ++kj) {
        const float p = __expf(sf[kj][rr] - mn);
        sf[kj][rr] = p;
        ps += p;
      }
      ps += __shfl_xor(ps, 1);
      ps += __shfl_xor(ps, 2);
      ps += __shfl_xor(ps, 4);
      ps += __shfl_xor(ps, 8);
      lst[rr] = lst[rr] * sc + ps;
      mst[rr] = mn;
#pragma unroll
      for (int dj = 0; dj < 4; ++dj) accD[dj][rr] *= sc;
    }
#pragma unroll
    for (int rr = 0; rr < 4; ++rr) {
      const int ql = grp * 4 + rr;
      const int swz = (ql & 7) << 4;
      char* rowp = (char*)P + ql * 128;
#pragma unroll
      for (int kj = 0; kj < 4; ++kj) {
        const int byo = ((kj * 16 + l15) * 2) ^ swz;
        *(u16*)(rowp + byo) = f2bf(sf[kj][rr]);
      }
    }
    asm volatile("s_waitcnt lgkmcnt(0)" ::: "memory");
    __builtin_amdgcn_sched_barrier(0);
#pragma unroll
    for (int ks = 0; ks < 2; ++ks) {
      const int byo = (l15 * 128 + ks * 64 + grp * 16) ^ ((l15 & 7) << 4);
      const short8x pak = *(const short8x*)((const char*)P + byo);
      short8x vfk[4];
#pragma unroll
      for (int dj = 0; dj < 4; ++dj) {
        const int dh = dj * 16 + l15;
        vfk[dj] = *(const short8x*)(vgb + (size_t)dh * 4096 + kbase + ks * 32 + grp * 8);
      }
#pragma unroll
      for (int dj = 0; dj < 4; ++dj)
        accD[dj] = __builtin_amdgcn_mfma_f32_16x16x32_bf16(pak, vfk[dj], accD[dj], 0, 0, 0);
    }
    asm volatile("s_waitcnt lgkmcnt(0)" ::: "memory");
    __builtin_amdgcn_sched_barrier(0);
  }

#pragma unroll
  for (int rr = 0; rr < 4; ++rr) {
    const float inv = 1.f / lst[rr];
    const int srow = clss[w * 16 + grp * 4 + rr];
    u16* o = aout + ((size_t)b * 4096 + srow) * 768 + h * 64;
#pragma unroll
    for (int dj = 0; dj < 4; ++dj)
      o[dj * 16 + l15] = f2bf(accD[dj][rr] * inv);
  }
}

// ---------------------------------------------------------------------------
extern "C" void kernel_launch(void* const* d_in, const int* in_sizes, int n_in,
                              void* d_out, int out_size, void* d_ws, size_t ws_size,
                              hipStream_t stream) {
  (void)in_sizes; (void)n_in; (void)out_size; (void)ws_size;
  const int* x = (const int*)d_in[0];
  const int* mask = (const int*)d_in[1];
  const int* clss = (const int*)d_in[2];
  const float* emb = (const float*)d_in[3];
  const float* pos = (const float*)d_in[4];
  const float* wq = (const float*)d_in[5];
  const float* wk = (const float*)d_in[6];
  const float* wv = (const float*)d_in[7];
  const float* wo = (const float*)d_in[8];
  const float* wqg = (const float*)d_in[9];
  const float* wkg = (const float*)d_in[10];
  const float* wvg = (const float*)d_in[11];
  float* out = (float*)d_out;

  char* ws = (char*)d_ws;
  size_t off = 0;
  auto alloc = [&](size_t n) { char* p = ws + off; off = (off + n + 255) & ~(size_t)255; return p; };
  const size_t SZ = (size_t)2 * 12 * 4096 * 64 * 2;  // one (B,H,S,DH) bf16 buffer
  u16* hb = (u16*)alloc(SZ);
  u16* wt = (u16*)alloc((size_t)7 * 768 * 768 * 2);
  u16* qb = (u16*)alloc(SZ);
  u16* kb = (u16*)alloc(SZ);
  u16* vb = (u16*)alloc(SZ);
  u16* kgb = (u16*)alloc(SZ);
  u16* vgb = (u16*)alloc(SZ);
  u16* qgb = (u16*)alloc(SZ);
  u16* vts = (u16*)alloc(SZ);
  u16* vgts = (u16*)alloc(SZ);
  u16* kcls = (u16*)alloc((size_t)24 * 64 * 64 * 2);
  u16* vtcls = (u16*)alloc((size_t)24 * 64 * 64 * 2);
  u8* mcls = (u8*)alloc(256);
  u8* isg = (u8*)alloc(4096);
  u16* aout = (u16*)alloc(SZ);

  WPtrs wp;
  wp.p[0] = wq; wp.p[1] = wk; wp.p[2] = wv; wp.p[3] = wkg; wp.p[4] = wvg; wp.p[5] = wqg; wp.p[6] = wo;

  wconv_kernel<<<dim3(144, 7), 256, 0, stream>>>(wp, wt);
  embed_kernel<<<2048, 256, 0, stream>>>(x, emb, pos, hb);
  isg_kernel<<<1, 256, 0, stream>>>(clss, isg);

  Outs6 o6;
  o6.p[0] = qb; o6.p[1] = kb; o6.p[2] = vb; o6.p[3] = kgb; o6.p[4] = vgb; o6.p[5] = qgb;
  gemm_kernel<0><<<dim3(36, 64), 256, 0, stream>>>(hb, wt, o6, nullptr);

  transp_kernel<<<dim3(1536, 2), 256, 0, stream>>>(vb, vts, vgb, vgts);
  gcls_kernel<<<24, 256, 0, stream>>>(kb, vb, clss, mask, kcls, vtcls, mcls);

  band_kernel<<<384, 256, 0, stream>>>(qb, kb, vts, kcls, vtcls, mcls, mask, isg, aout);
  og_kernel<<<24, 256, 0, stream>>>(qgb, kgb, vgts, clss, mask, aout);

  Outs6 dummy = {};
  gemm_kernel<1><<<dim3(6, 64), 256, 0, stream>>>(aout, wt + (size_t)6 * 768 * 768, dummy, out);
}

// Round 2
// 312.633 us; speedup vs baseline: 1.4128x; 1.4128x over previous
//
#include <hip/hip_runtime.h>
#include <stdint.h>

typedef unsigned short u16;
typedef unsigned char u8;
typedef __attribute__((ext_vector_type(8))) short short8x;
typedef __attribute__((ext_vector_type(4))) float f32x4;

#define DEV static __device__ __forceinline__

DEV u16 f2bf(float f) {
  union { float f; unsigned u; } v; v.f = f;
  unsigned r = v.u + 0x7FFFu + ((v.u >> 16) & 1u);
  return (u16)(r >> 16);
}
DEV int imin(int a, int b) { return a < b ? a : b; }
DEV int imax(int a, int b) { return a > b ? a : b; }

DEV void gload16(const void* g, void* l) {
  __builtin_amdgcn_global_load_lds((const __attribute__((address_space(1))) void*)g,
                                   (__attribute__((address_space(3))) void*)l, 16, 0, 0);
}

// ---------------------------------------------------------------------------
// Weight convert+transpose: w[k][n] fp32 -> wt[mat][n][k] bf16 (7 mats)
struct WPtrs { const float* p[7]; };

__global__ __launch_bounds__(256) void wconv_kernel(WPtrs wp, u16* __restrict__ wt) {
  const int mat = blockIdx.y;
  const int kt = blockIdx.x % 12, nt = blockIdx.x / 12;
  const float* __restrict__ w = wp.p[mat];
  __shared__ float tile[64][72];
  const int t = threadIdx.x;
  {
    const int kk = t >> 2, n0 = (t & 3) * 16;
    const float* src = w + (size_t)(kt * 64 + kk) * 768 + nt * 64 + n0;
#pragma unroll
    for (int i = 0; i < 4; ++i)
      *(float4*)&tile[kk][n0 + i * 4] = *(const float4*)(src + i * 4);
  }
  __syncthreads();
  {
    const int nn = t >> 2, k0 = (t & 3) * 16;
    u16* dst = wt + (size_t)(mat * 768 + nt * 64 + nn) * 768 + kt * 64 + k0;
    short8x v0, v1;
#pragma unroll
    for (int j = 0; j < 8; ++j) {
      v0[j] = (short)f2bf(tile[k0 + j][nn]);
      v1[j] = (short)f2bf(tile[k0 + 8 + j][nn]);
    }
    *(short8x*)dst = v0;
    *(short8x*)(dst + 8) = v1;
  }
}

// ---------------------------------------------------------------------------
// h = emb[x] + pos  -> bf16  (8192 x 768)
__global__ __launch_bounds__(256) void embed_kernel(const int* __restrict__ x, const float* __restrict__ emb,
                                                    const float* __restrict__ pos, u16* __restrict__ hb) {
  const int n4 = 2 * 4096 * 192;
  for (int i = blockIdx.x * 256 + threadIdx.x; i < n4; i += gridDim.x * 256) {
    const int r = i / 192;
    const int d4 = i - r * 192;
    const int s = r & 4095;
    const int tok = x[r];
    const float4 e = *(const float4*)(emb + (size_t)tok * 768 + d4 * 4);
    const float4 p = *(const float4*)(pos + (size_t)s * 768 + d4 * 4);
    union { u16 u[4]; uint2 v; } o;
    o.u[0] = f2bf(e.x + p.x);
    o.u[1] = f2bf(e.y + p.y);
    o.u[2] = f2bf(e.z + p.z);
    o.u[3] = f2bf(e.w + p.w);
    *(uint2*)(hb + (size_t)r * 768 + d4 * 4) = o.v;
  }
}

// ---------------------------------------------------------------------------
// isg (global-token flags) + kval[b][key] = mask && !isg  (band-key validity)
__global__ __launch_bounds__(256) void isg_kernel(const int* __restrict__ clss, const int* __restrict__ mask,
                                                  u8* __restrict__ isg, u8* __restrict__ kval) {
  const int t = threadIdx.x;
  for (int i = t; i < 4096; i += 256) isg[i] = 0;
  __syncthreads();
  if (t < 64) isg[clss[t]] = 1;
  __syncthreads();
  for (int b = 0; b < 2; ++b)
    for (int i = t; i < 4096; i += 256)
      kval[b * 4096 + i] = (u8)((mask[b * 4096 + i] != 0) & (isg[i] == 0));
}

// ---------------------------------------------------------------------------
// 128x128x32 bf16 MFMA GEMM, B pre-transposed (N x K), global_load_lds staging.
// MODE 0: A=h (8192x768), Bt=Wt cat (4608x768): write q,k,v,kg,vg,qg in (B,H,S,DH) bf16
// MODE 1: A=attn_out bf16 (8192x768), Bt=woT: write fp32 d_out row-major
struct Outs6 { u16* p[6]; };

template <int MODE>
__global__ __launch_bounds__(256) void gemm_kernel(const u16* __restrict__ A, const u16* __restrict__ Bt,
                                                   Outs6 outs, float* __restrict__ outF) {
  __shared__ __align__(16) u16 smA[128 * 32];
  __shared__ __align__(16) u16 smB[128 * 32];
  const int t = threadIdx.x;
  const int l = t & 63, w = t >> 6;
  const int l15 = l & 15, grp = l >> 4;
  const int wm = w >> 1, wn = w & 1;
  const int m0 = blockIdx.y * 128, n0 = blockIdx.x * 128;
  const f32x4 zero4 = {0.f, 0.f, 0.f, 0.f};
  f32x4 acc[4][4];
#pragma unroll
  for (int mi = 0; mi < 4; ++mi)
#pragma unroll
    for (int ni = 0; ni < 4; ++ni) acc[mi][ni] = zero4;

  // staging geometry: wave w stages rows [32w, 32w+32) of A and B tiles; lane l
  // covers row 32w + (l>>2), elem col (l&3)*8; LDS dest = base + 16B*lane.
  const int srow = w * 32 + (l >> 2);
  const int scol = (l & 3) * 8;
  const u16* gA = A + (size_t)(m0 + srow) * 768 + scol;
  const u16* gB = Bt + (size_t)(n0 + srow) * 768 + scol;
  u16* lA = smA + w * 1024;
  u16* lB = smB + w * 1024;

  for (int kb = 0; kb < 24; ++kb) {
    __syncthreads();
    const size_t ko = (size_t)kb * 32;
    gload16(gA + ko, lA);
    gload16(gA + 16 * 768 + ko, lA + 512);
    gload16(gB + ko, lB);
    gload16(gB + 16 * 768 + ko, lB + 512);
    __syncthreads();
    short8x af[4], bfr[4];
#pragma unroll
    for (int mi = 0; mi < 4; ++mi)
      af[mi] = *(const short8x*)(smA + (wm * 64 + mi * 16 + l15) * 32 + grp * 8);
#pragma unroll
    for (int ni = 0; ni < 4; ++ni)
      bfr[ni] = *(const short8x*)(smB + (wn * 64 + ni * 16 + l15) * 32 + grp * 8);
#pragma unroll
    for (int mi = 0; mi < 4; ++mi)
#pragma unroll
      for (int ni = 0; ni < 4; ++ni)
        acc[mi][ni] = __builtin_amdgcn_mfma_f32_16x16x32_bf16(af[mi], bfr[ni], acc[mi][ni], 0, 0, 0);
  }

  if (MODE == 0) {
    const int mat = blockIdx.x / 6;               // 6 col-blocks per 768-wide matrix
    const int inn0 = n0 - mat * 768 + wn * 64;
    const float scl = (mat == 0 || mat == 5) ? 0.125f : 1.0f;  // q, qg scaled by DH^-0.5
    u16* __restrict__ base = outs.p[mat];
#pragma unroll
    for (int mi = 0; mi < 4; ++mi)
#pragma unroll
      for (int ni = 0; ni < 4; ++ni) {
        const int col = inn0 + ni * 16 + l15;
        const int hd = col >> 6, dh = col & 63;
#pragma unroll
        for (int rr = 0; rr < 4; ++rr) {
          const int row = m0 + wm * 64 + mi * 16 + grp * 4 + rr;
          const int b = row >> 12, s = row & 4095;
          base[((size_t)(b * 12 + hd) * 4096 + s) * 64 + dh] = f2bf(acc[mi][ni][rr] * scl);
        }
      }
  } else {
#pragma unroll
    for (int mi = 0; mi < 4; ++mi)
#pragma unroll
      for (int rr = 0; rr < 4; ++rr) {
        const int row = m0 + wm * 64 + mi * 16 + grp * 4 + rr;
#pragma unroll
        for (int ni = 0; ni < 4; ++ni) {
          const int col = n0 + wn * 64 + ni * 16 + l15;
          outF[(size_t)row * 768 + col] = acc[mi][ni][rr];
        }
      }
  }
}

// ---------------------------------------------------------------------------
// (B,H,S,DH) -> (B,H,DH,S) bf16, two buffers (v->vT, vg->vgT)
__global__ __launch_bounds__(256) void transp_kernel(const u16* __restrict__ in0, u16* __restrict__ out0,
                                                     const u16* __restrict__ in1, u16* __restrict__ out1) {
  const u16* src = blockIdx.y ? in1 : in0;
  u16* dst = blockIdx.y ? out1 : out0;
  const int bh = blockIdx.x >> 6;
  const int s0 = (blockIdx.x & 63) << 6;
  __shared__ u16 tile[64][80];
  const int t = threadIdx.x;
  {
    const int sl = t >> 2, d0 = (t & 3) * 16;
    const u16* p = src + ((size_t)bh * 4096 + s0 + sl) * 64 + d0;
    *(short8x*)&tile[sl][d0] = *(const short8x*)p;
    *(short8x*)&tile[sl][d0 + 8] = *(const short8x*)(p + 8);
  }
  __syncthreads();
  {
    const int dh = t >> 2, q0 = (t & 3) * 16;
    short8x v0, v1;
#pragma unroll
    for (int j = 0; j < 8; ++j) {
      v0[j] = (short)tile[q0 + j][dh];
      v1[j] = (short)tile[q0 + 8 + j][dh];
    }
    u16* o = dst + ((size_t)bh * 64 + dh) * 4096 + s0 + q0;
    *(short8x*)o = v0;
    *(short8x*)(o + 8) = v1;
  }
}

// ---------------------------------------------------------------------------
// Gather K rows at clss -> kcls[bh][g][dh]; v rows at clss transposed -> vtcls[bh][dh][g]; mask at clss.
__global__ __launch_bounds__(256) void gcls_kernel(const u16* __restrict__ kB, const u16* __restrict__ vB,
                                                   const int* __restrict__ clss, const int* __restrict__ mask,
                                                   u16* __restrict__ kcls, u16* __restrict__ vtcls,
                                                   u8* __restrict__ mcls) {
  const int bh = blockIdx.x;
  const int b = bh / 12;
  __shared__ u16 tile[64][80];
  const int t = threadIdx.x;
  {
    const int g = t >> 2, d0 = (t & 3) * 16;
    const int row = clss[g];
    const u16* pk = kB + ((size_t)bh * 4096 + row) * 64 + d0;
    u16* ok = kcls + ((size_t)bh * 64 + g) * 64 + d0;
    *(short8x*)ok = *(const short8x*)pk;
    *(short8x*)(ok + 8) = *(const short8x*)(pk + 8);
    const u16* pv = vB + ((size_t)bh * 4096 + row) * 64 + d0;
    *(short8x*)&tile[g][d0] = *(const short8x*)pv;
    *(short8x*)&tile[g][d0 + 8] = *(const short8x*)(pv + 8);
  }
  if (t < 64) mcls[b * 64 + t] = (mask[(size_t)b * 4096 + clss[t]] != 0) ? 1 : 0;
  __syncthreads();
  {
    const int dh = t >> 2, g0 = (t & 3) * 16;
    short8x v0, v1;
#pragma unroll
    for (int j = 0; j < 8; ++j) {
      v0[j] = (short)tile[g0 + j][dh];
      v1[j] = (short)tile[g0 + 8 + j][dh];
    }
    u16* o = vtcls + ((size_t)bh * 64 + dh) * 64 + g0;
    *(short8x*)o = v0;
    *(short8x*)(o + 8) = v1;
  }
}

// ---------------------------------------------------------------------------
// Band + global-key attention. 768 blocks; wave w owns 32 queries.
// Flash loop over 64-key tiles covering [q0-256, q0+287], then the 64 clss keys.
__global__ __launch_bounds__(256, 3) void band_kernel(
    const u16* __restrict__ qB, const u16* __restrict__ kB, const u16* __restrict__ vT,
    const u16* __restrict__ kcls, const u16* __restrict__ vtcls, const u8* __restrict__ mcls,
    const u8* __restrict__ kval, u16* __restrict__ aout) {
  int bid = blockIdx.x;
  bid = (bid & 7) * 96 + (bid >> 3);   // XCD chunking: each XCD gets 3 whole (b,h) panels
  const int qblk = bid & 31;
  const int h = (bid >> 5) % 12;
  const int b = bid / 384;
  const int t = threadIdx.x;
  const int w = t >> 6, l = t & 63, l15 = l & 15, grp = l >> 4;
  const int bh = b * 12 + h;
  const int q0 = qblk * 128 + w * 32;

  __shared__ u16 Pt[4][2][2048];  // per-wave double-buffered 32x64 bf16 P (XOR-swizzled)

  const u16* qb = qB + ((size_t)bh * 4096 + q0) * 64;
  short8x qf[2][2];
#pragma unroll
  for (int qi = 0; qi < 2; ++qi)
#pragma unroll
    for (int ks = 0; ks < 2; ++ks)
      qf[qi][ks] = *(const short8x*)(qb + (qi * 16 + l15) * 64 + ks * 32 + grp * 8);

  const f32x4 zero4 = {0.f, 0.f, 0.f, 0.f};
  f32x4 accD[2][4];
  float mst[2][4], lst[2][4];
#pragma unroll
  for (int qi = 0; qi < 2; ++qi)
#pragma unroll
    for (int j = 0; j < 4; ++j) { accD[qi][j] = zero4; mst[qi][j] = -60.f; lst[qi][j] = 0.f; }

  const u16* kbh = kB + (size_t)bh * 4096 * 64;
  const u16* vbh = vT + (size_t)bh * 64 * 4096;
  const u16* kcb = kcls + (size_t)bh * 4096;
  const u16* vcb = vtcls + (size_t)bh * 4096;
  const u8* kvb = kval + b * 4096;

  const int tlo = imax(0, (q0 - 256) >> 6);
  const int thi = imin(63, (q0 + 287) >> 6);

  for (int tt = tlo; tt <= thi + 1; ++tt) {
    const bool isG = (tt == thi + 1);
    const int kbase = isG ? 0 : tt * 64;

    int kok[4], keyv[4];
    const u16* krow[4];
#pragma unroll
    for (int kj = 0; kj < 4; ++kj) {
      const int key = kbase + kj * 16 + l15;
      keyv[kj] = key;
      if (isG) {
        kok[kj] = mcls[b * 64 + key];
        krow[kj] = kcb + key * 64;
      } else {
        kok[kj] = kvb[key];
        krow[kj] = kbh + (size_t)key * 64;
      }
    }

    f32x4 sf[2][4];
#pragma unroll
    for (int qi = 0; qi < 2; ++qi)
#pragma unroll
      for (int kj = 0; kj < 4; ++kj) sf[qi][kj] = zero4;
#pragma unroll
    for (int ks = 0; ks < 2; ++ks) {
      short8x kfk[4];
#pragma unroll
      for (int kj = 0; kj < 4; ++kj) kfk[kj] = *(const short8x*)(krow[kj] + ks * 32 + grp * 8);
#pragma unroll
      for (int qi = 0; qi < 2; ++qi)
#pragma unroll
        for (int kj = 0; kj < 4; ++kj)
          sf[qi][kj] = __builtin_amdgcn_mfma_f32_16x16x32_bf16(qf[qi][ks], kfk[kj], sf[qi][kj], 0, 0, 0);
    }

    // mask + online softmax
#pragma unroll
    for (int qi = 0; qi < 2; ++qi) {
      const int qr0 = q0 + qi * 16 + grp * 4;
      float tm[4];
#pragma unroll
      for (int rr = 0; rr < 4; ++rr) tm[rr] = -1e30f;
#pragma unroll
      for (int kj = 0; kj < 4; ++kj)
#pragma unroll
        for (int rr = 0; rr < 4; ++rr) {
          int valid = kok[kj];
          if (!isG) {
            const int rel = keyv[kj] - (qr0 + rr);
            valid = valid & (int)(rel >= -256) & (int)(rel <= 256);
          }
          const float sv = valid ? sf[qi][kj][rr] : -1e30f;
          sf[qi][kj][rr] = sv;
          tm[rr] = fmaxf(tm[rr], sv);
        }
#pragma unroll
      for (int rr = 0; rr < 4; ++rr) {
        float v = tm[rr];
        v = fmaxf(v, __shfl_xor(v, 1));
        v = fmaxf(v, __shfl_xor(v, 2));
        v = fmaxf(v, __shfl_xor(v, 4));
        v = fmaxf(v, __shfl_xor(v, 8));
        const float mo = mst[qi][rr];
        const float mn = fmaxf(mo, v);  // floor -60 keeps masked-exp at exact 0
        const float sc = __expf(mo - mn);
        float ps = 0.f;
#pragma unroll
        for (int kj = 0; kj < 4; ++kj) {
          const float p = __expf(sf[qi][kj][rr] - mn);
          sf[qi][kj][rr] = p;
          ps += p;
        }
        ps += __shfl_xor(ps, 1);
        ps += __shfl_xor(ps, 2);
        ps += __shfl_xor(ps, 4);
        ps += __shfl_xor(ps, 8);
        lst[qi][rr] = lst[qi][rr] * sc + ps;
        mst[qi][rr] = mn;
#pragma unroll
        for (int dj = 0; dj < 4; ++dj) accD[qi][dj][rr] *= sc;
      }
    }

    // P -> LDS bf16 (row q*128B + key*2B, XOR swizzle bits 4-6 by row&7)
    u16* P = Pt[w][tt & 1];
#pragma unroll
    for (int qi = 0; qi < 2; ++qi)
#pragma unroll
      for (int rr = 0; rr < 4; ++rr) {
        const int ql = qi * 16 + grp * 4 + rr;
        const int swz = (ql & 7) << 4;
        char* rowp = (char*)P + ql * 128;
#pragma unroll
        for (int kj = 0; kj < 4; ++kj) {
          const int byo = ((kj * 16 + l15) * 2) ^ swz;
          *(u16*)(rowp + byo) = f2bf(sf[qi][kj][rr]);
        }
      }
    asm volatile("s_waitcnt lgkmcnt(0)" ::: "memory");
    __builtin_amdgcn_sched_barrier(0);

    // PV: A = P (from LDS), B = vT (global, K-contiguous)
#pragma unroll
    for (int ks = 0; ks < 2; ++ks) {
      short8x pak[2], vfk[4];
#pragma unroll
      for (int qi = 0; qi < 2; ++qi) {
        const int ql = qi * 16 + l15;
        const int byo = (ql * 128 + ks * 64 + grp * 16) ^ ((ql & 7) << 4);
        pak[qi] = *(const short8x*)((const char*)P + byo);
      }
#pragma unroll
      for (int dj = 0; dj < 4; ++dj) {
        const int dh = dj * 16 + l15;
        const u16* vr = isG ? (vcb + dh * 64) : (vbh + (size_t)dh * 4096 + kbase);
        vfk[dj] = *(const short8x*)(vr + ks * 32 + grp * 8);
      }
#pragma unroll
      for (int qi = 0; qi < 2; ++qi)
#pragma unroll
        for (int dj = 0; dj < 4; ++dj)
          accD[qi][dj] = __builtin_amdgcn_mfma_f32_16x16x32_bf16(pak[qi], vfk[dj], accD[qi][dj], 0, 0, 0);
    }
  }

  // finalize: divide by row sums, store (B,S,D) bf16
  u16* ob = aout + ((size_t)b * 4096 + q0) * 768 + h * 64;
#pragma unroll
  for (int qi = 0; qi < 2; ++qi)
#pragma unroll
    for (int rr = 0; rr < 4; ++rr) {
      const float inv = 1.f / lst[qi][rr];
      const int row = qi * 16 + grp * 4 + rr;
#pragma unroll
      for (int dj = 0; dj < 4; ++dj)
        ob[(size_t)row * 768 + dj * 16 + l15] = f2bf(accD[qi][dj][rr] * inv);
    }
}

// ---------------------------------------------------------------------------
// Global-token attention, part 1: one wave per (b,h,kslice); 8 key-tiles each.
// Writes partial (m, l, acc) for flash-decoding merge.
__global__ __launch_bounds__(64) void ogp_kernel(
    const u16* __restrict__ qgB, const u16* __restrict__ kgB, const u16* __restrict__ vgT,
    const int* __restrict__ clss, const int* __restrict__ mask,
    float* __restrict__ pm, float* __restrict__ pl, float* __restrict__ pacc) {
  const int blk = blockIdx.x;  // bh*8 + slice
  const int bh = blk >> 3, sl = blk & 7;
  const int b = bh / 12;
  const int l = threadIdx.x, l15 = l & 15, grp = l >> 4;

  __shared__ u16 P[4096];  // 64x64 bf16 P tile (XOR-swizzled)

  const u16* qgb = qgB + (size_t)bh * 4096 * 64;
  const u16* kgb = kgB + (size_t)bh * 4096 * 64;
  const u16* vgb = vgT + (size_t)bh * 64 * 4096;

  short8x qf[4][2];
#pragma unroll
  for (int qi = 0; qi < 4; ++qi) {
    const int srow = clss[qi * 16 + l15];
    qf[qi][0] = *(const short8x*)(qgb + (size_t)srow * 64 + grp * 8);
    qf[qi][1] = *(const short8x*)(qgb + (size_t)srow * 64 + 32 + grp * 8);
  }

  const f32x4 zero4 = {0.f, 0.f, 0.f, 0.f};
  f32x4 accD[4][4];
  float mst[4][4], lst[4][4];
#pragma unroll
  for (int qi = 0; qi < 4; ++qi)
#pragma unroll
    for (int j = 0; j < 4; ++j) { accD[qi][j] = zero4; mst[qi][j] = -60.f; lst[qi][j] = 0.f; }

  for (int tt = sl * 8; tt < sl * 8 + 8; ++tt) {
    const int kbase = tt * 64;
    int kok[4];
    f32x4 sf[4][4];
#pragma unroll
    for (int kj = 0; kj < 4; ++kj) {
      kok[kj] = (mask[b * 4096 + kbase + kj * 16 + l15] != 0);
#pragma unroll
      for (int qi = 0; qi < 4; ++qi) sf[qi][kj] = zero4;
    }
#pragma unroll
    for (int ks = 0; ks < 2; ++ks) {
      short8x kfk[4];
#pragma unroll
      for (int kj = 0; kj < 4; ++kj)
        kfk[kj] = *(const short8x*)(kgb + (size_t)(kbase + kj * 16 + l15) * 64 + ks * 32 + grp * 8);
#pragma unroll
      for (int qi = 0; qi < 4; ++qi)
#pragma unroll
        for (int kj = 0; kj < 4; ++kj)
          sf[qi][kj] = __builtin_amdgcn_mfma_f32_16x16x32_bf16(qf[qi][ks], kfk[kj], sf[qi][kj], 0, 0, 0);
    }
#pragma unroll
    for (int qi = 0; qi < 4; ++qi) {
      float tm[4];
#pragma unroll
      for (int rr = 0; rr < 4; ++rr) tm[rr] = -1e30f;
#pragma unroll
      for (int kj = 0; kj < 4; ++kj)
#pragma unroll
        for (int rr = 0; rr < 4; ++rr) {
          const float sv = kok[kj] ? sf[qi][kj][rr] : -1e30f;
          sf[qi][kj][rr] = sv;
          tm[rr] = fmaxf(tm[rr], sv);
        }
#pragma unroll
      for (int rr = 0; rr < 4; ++rr) {
        float v = tm[rr];
        v = fmaxf(v, __shfl_xor(v, 1));
        v = fmaxf(v, __shfl_xor(v, 2));
        v = fmaxf(v, __shfl_xor(v, 4));
        v = fmaxf(v, __shfl_xor(v, 8));
        const float mo = mst[qi][rr];
        const float mn = fmaxf(mo, v);
        const float sc = __expf(mo - mn);
        float ps = 0.f;
#pragma unroll
        for (int kj = 0; kj < 4; ++kj) {
          const float p = __expf(sf[qi][kj][rr] - mn);
          sf[qi][kj][rr] = p;
          ps += p;
        }
        ps += __shfl_xor(ps, 1);
        ps += __shfl_xor(ps, 2);
        ps += __shfl_xor(ps, 4);
        ps += __shfl_xor(ps, 8);
        lst[qi][rr] = lst[qi][rr] * sc + ps;
        mst[qi][rr] = mn;
#pragma unroll
        for (int dj = 0; dj < 4; ++dj) accD[qi][dj][rr] *= sc;
      }
    }
#pragma unroll
    for (int qi = 0; qi < 4; ++qi)
#pragma unroll
      for (int rr = 0; rr < 4; ++rr) {
        const int ql = qi * 16 + grp * 4 + rr;
        const int swz = (ql & 7) << 4;
        char* rowp = (char*)P + ql * 128;
#pragma unroll
        for (int kj = 0; kj < 4; ++kj) {
          const int byo = ((kj * 16 + l15) * 2) ^ swz;
          *(u16*)(rowp + byo) = f2bf(sf[qi][kj][rr]);
        }
      }
    asm volatile("s_waitcnt lgkmcnt(0)" ::: "memory");
    __builtin_amdgcn_sched_barrier(0);
#pragma unroll
    for (int ks = 0; ks < 2; ++ks) {
      short8x pak[4], vfk[4];
#pragma unroll
      for (int qi = 0; qi < 4; ++qi) {
        const int ql = qi * 16 + l15;
        const int byo = (ql * 128 + ks * 64 + grp * 16) ^ ((ql & 7) << 4);
        pak[qi] = *(const short8x*)((const char*)P + byo);
      }
#pragma unroll
      for (int dj = 0; dj < 4; ++dj) {
        const int dh = dj * 16 + l15;
        vfk[dj] = *(const short8x*)(vgb + (size_t)dh * 4096 + kbase + ks * 32 + grp * 8);
      }
#pragma unroll
      for (int qi = 0; qi < 4; ++qi)
#pragma unroll
        for (int dj = 0; dj < 4; ++dj)
          accD[qi][dj] = __builtin_amdgcn_mfma_f32_16x16x32_bf16(pak[qi], vfk[dj], accD[qi][dj], 0, 0, 0);
    }
    asm volatile("s_waitcnt lgkmcnt(0)" ::: "memory");
    __builtin_amdgcn_sched_barrier(0);
  }

#pragma unroll
  for (int qi = 0; qi < 4; ++qi)
#pragma unroll
    for (int dj = 0; dj < 4; ++dj)
#pragma unroll
      for (int rr = 0; rr < 4; ++rr) {
        const int row = qi * 16 + grp * 4 + rr;
        pacc[(size_t)blk * 4096 + row * 64 + dj * 16 + l15] = accD[qi][dj][rr];
      }
  if (l15 == 0)
#pragma unroll
    for (int qi = 0; qi < 4; ++qi)
#pragma unroll
      for (int rr = 0; rr < 4; ++rr) {
        const int row = qi * 16 + grp * 4 + rr;
        pm[blk * 64 + row] = mst[qi][rr];
        pl[blk * 64 + row] = lst[qi][rr];
      }
}

// ---------------------------------------------------------------------------
// Global-token attention merge: combine 8 key-slice partials, overwrite clss rows of aout.
__global__ __launch_bounds__(256) void ogm_kernel(const float* __restrict__ pm, const float* __restrict__ pl,
                                                  const float* __restrict__ pacc, const int* __restrict__ clss,
                                                  u16* __restrict__ aout) {
  const int bh = blockIdx.x;
  const int b = bh / 12, h = bh % 12;
  const int t = threadIdx.x;
  const int r = t >> 2, cs = (t & 3) * 16;
  float mv[8];
  float M = -1e30f;
#pragma unroll
  for (int s = 0; s < 8; ++s) {
    mv[s] = pm[(bh * 8 + s) * 64 + r];
    M = fmaxf(M, mv[s]);
  }
  float L = 0.f, f[8];
#pragma unroll
  for (int s = 0; s < 8; ++s) {
    f[s] = __expf(mv[s] - M);
    L += pl[(bh * 8 + s) * 64 + r] * f[s];
  }
  float o[16];
#pragma unroll
  for (int j = 0; j < 16; ++j) o[j] = 0.f;
#pragma unroll
  for (int s = 0; s < 8; ++s) {
    const float* pr = pacc + (size_t)(bh * 8 + s) * 4096 + r * 64 + cs;
#pragma unroll
    for (int j4 = 0; j4 < 4; ++j4) {
      const float4 a = *(const float4*)(pr + j4 * 4);
      o[j4 * 4 + 0] += a.x * f[s];
      o[j4 * 4 + 1] += a.y * f[s];
      o[j4 * 4 + 2] += a.z * f[s];
      o[j4 * 4 + 3] += a.w * f[s];
    }
  }
  const float inv = 1.f / L;
  short8x v0, v1;
#pragma unroll
  for (int j = 0; j < 8; ++j) {
    v0[j] = (short)f2bf(o[j] * inv);
    v1[j] = (short)f2bf(o[8 + j] * inv);
  }
  u16* op = aout + ((size_t)b * 4096 + clss[r]) * 768 + h * 64 + cs;
  *(short8x*)op = v0;
  *(short8x*)(op + 8) = v1;
}

// ---------------------------------------------------------------------------
extern "C" void kernel_launch(void* const* d_in, const int* in_sizes, int n_in,
                              void* d_out, int out_size, void* d_ws, size_t ws_size,
                              hipStream_t stream) {
  (void)in_sizes; (void)n_in; (void)out_size; (void)ws_size;
  const int* x = (const int*)d_in[0];
  const int* mask = (const int*)d_in[1];
  const int* clss = (const int*)d_in[2];
  const float* emb = (const float*)d_in[3];
  const float* pos = (const float*)d_in[4];
  const float* wq = (const float*)d_in[5];
  const float* wk = (const float*)d_in[6];
  const float* wv = (const float*)d_in[7];
  const float* wo = (const float*)d_in[8];
  const float* wqg = (const float*)d_in[9];
  const float* wkg = (const float*)d_in[10];
  const float* wvg = (const float*)d_in[11];
  float* out = (float*)d_out;

  char* ws = (char*)d_ws;
  size_t off = 0;
  auto alloc = [&](size_t n) { char* p = ws + off; off = (off + n + 255) & ~(size_t)255; return p; };
  const size_t SZ = (size_t)2 * 12 * 4096 * 64 * 2;  // one (B,H,S,DH) bf16 buffer
  u16* hb = (u16*)alloc(SZ);
  u16* wt = (u16*)alloc((size_t)7 * 768 * 768 * 2);
  u16* qb = (u16*)alloc(SZ);
  u16* kb = (u16*)alloc(SZ);
  u16* vb = (u16*)alloc(SZ);
  u16* kgb = (u16*)alloc(SZ);
  u16* vgb = (u16*)alloc(SZ);
  u16* qgb = (u16*)alloc(SZ);
  u16* vts = (u16*)alloc(SZ);
  u16* vgts = (u16*)alloc(SZ);
  u16* kcls = (u16*)alloc((size_t)24 * 64 * 64 * 2);
  u16* vtcls = (u16*)alloc((size_t)24 * 64 * 64 * 2);
  u8* mcls = (u8*)alloc(256);
  u8* isg = (u8*)alloc(4096);
  u8* kval = (u8*)alloc(2 * 4096);
  u16* aout = (u16*)alloc(SZ);
  float* pm = (float*)alloc((size_t)192 * 64 * 4);
  float* pl = (float*)alloc((size_t)192 * 64 * 4);
  float* pacc = (float*)alloc((size_t)192 * 4096 * 4);

  WPtrs wp;
  wp.p[0] = wq; wp.p[1] = wk; wp.p[2] = wv; wp.p[3] = wkg; wp.p[4] = wvg; wp.p[5] = wqg; wp.p[6] = wo;

  wconv_kernel<<<dim3(144, 7), 256, 0, stream>>>(wp, wt);
  embed_kernel<<<2048, 256, 0, stream>>>(x, emb, pos, hb);
  isg_kernel<<<1, 256, 0, stream>>>(clss, mask, isg, kval);

  Outs6 o6;
  o6.p[0] = qb; o6.p[1] = kb; o6.p[2] = vb; o6.p[3] = kgb; o6.p[4] = vgb; o6.p[5] = qgb;
  gemm_kernel<0><<<dim3(36, 64), 256, 0, stream>>>(hb, wt, o6, nullptr);

  transp_kernel<<<dim3(1536, 2), 256, 0, stream>>>(vb, vts, vgb, vgts);
  gcls_kernel<<<24, 256, 0, stream>>>(kb, vb, clss, mask, kcls, vtcls, mcls);

  ogp_kernel<<<192, 64, 0, stream>>>(qgb, kgb, vgts, clss, mask, pm, pl, pacc);
  band_kernel<<<768, 256, 0, stream>>>(qb, kb, vts, kcls, vtcls, mcls, kval, aout);
  ogm_kernel<<<24, 256, 0, stream>>>(pm, pl, pacc, clss, aout);

  Outs6 dummy = {};
  gemm_kernel<1><<<dim3(6, 64), 256, 0, stream>>>(aout, wt + (size_t)6 * 768 * 768, dummy, out);
}